// Round 9
// baseline (356.437 us; speedup 1.0000x reference)
//
#include <hip/hip_runtime.h>
#include <hip/hip_bf16.h>
#include <math.h>

// ============================================================================
// SelfAttention B=4 S=4096 D=512, fp32 in/out, bf16 MFMA internally.
//
// R9 changes vs R8 (R8: depth-1 prefetch gave only -2.5% on EXP; per-iter
// compute ~300-400cyc vs ~900cyc HBM latency -> need prefetch depth 2-3):
//  - NS-stage rotating pipeline (template): prologue issues NS-1 tiles;
//    steady state issues tile iter+NS-1 then waits vmcnt((NS-1)*LPT), so a
//    tile's loads get NS-1 compute-iterations to land.
//  - EXP/QKV: NS=3, BK=32 (3x16KB staging, LDS 48KB -> 3 blocks/CU).
//  - DIV: NS=4, BK=32 (4x12KB, 48KB -> 3 blocks/CU, depth-3).
//
// GEMM core otherwise = R8: 256 thr / 4 waves 2x2, global_load_lds width=16,
// XOR chunk swizzle (free 2-way), raw s_barrier pair + sched_barrier(0),
// padded LDS C-tile epilogue with 16B stores.
// Q pre-scaled by 1/sqrt(512)*log2(e) => EXP epilogue = one v_exp_f32/elem.
// Softmax needs no max-subtraction: |score| <= |q||k|/sqrt(512) ~ 7.5.
// ============================================================================

typedef __bf16 bfx8 __attribute__((ext_vector_type(8)));
typedef __bf16 bfx4 __attribute__((ext_vector_type(4)));
typedef float  fx4  __attribute__((ext_vector_type(4)));

#define HID   512
#define NBATCH 4
#define SEQ   4096
#define MROWS (NBATCH * SEQ)

#if __has_builtin(__builtin_amdgcn_exp2f)
#define EXPFN(x) __builtin_amdgcn_exp2f(x)
#define QSCALE 0.06375871589f   /* (1/sqrt(512)) * log2(e) */
#else
#define EXPFN(x) __expf(x)
#define QSCALE 0.04419417382f   /* 1/sqrt(512) */
#endif

constexpr int MODE_QKV = 0;  // C0=Q(bf16,scaled) C1=K(bf16) C2=Vt(bf16,transposed)
constexpr int MODE_EXP = 2;  // C0 bf16 = exp2(acc), atomic rowsum
constexpr int MODE_DIV = 3;  // C0 fp32 = acc / rowsum[m]

// s_waitcnt imm: vmcnt=n (bits [3:0],[15:14]), expcnt=7 nowait, lgkmcnt=15 nowait
constexpr int WVM(int n) { return (n & 15) | ((n >> 4) << 14) | (7 << 4) | (15 << 8); }

// ---------------------------------------------------------------------------
__device__ __forceinline__ void gload_lds16(const __bf16* gsrc, __bf16* ldst) {
  __builtin_amdgcn_global_load_lds(
      (const __attribute__((address_space(1))) unsigned int*)gsrc,
      (__attribute__((address_space(3))) unsigned int*)ldst,
      16, 0, 0);
}

// ---------------------------------------------------------------------------
__global__ void prep_x_kernel(const float* __restrict__ X, __bf16* __restrict__ Xb) {
  int i = (blockIdx.x * 256 + threadIdx.x) * 4;
  const float4 v = *(const float4*)(X + i);
  bfx4 o;
  o[0] = (__bf16)v.x; o[1] = (__bf16)v.y; o[2] = (__bf16)v.z; o[3] = (__bf16)v.w;
  *(bfx4*)(Xb + i) = o;
}

__global__ void prep_w_kernel(const float* __restrict__ Wq, const float* __restrict__ Wk,
                              const float* __restrict__ Wv, __bf16* __restrict__ Wt) {
  int id  = blockIdx.x * 256 + threadIdx.x;   // 0 .. 3*512*512-1
  int g   = id >> 18;
  int rem = id & ((1 << 18) - 1);
  int i   = rem >> 9;          // input dim (row of W)
  int o   = rem & 511;         // output dim (col of W) -- coalesced read
  const float* W = (g == 0) ? Wq : ((g == 1) ? Wk : Wv);
  Wt[(g << 18) + (o << 9) + i] = (__bf16)W[rem];
}

// ---------------------------------------------------------------------------
// C[M,N] = A[M,K] @ B[N,K]^T (+ mode epilogue).  TMxTN tile, BK=32,
// 256 threads = 4 waves 2x2 (wave tile (TM/2)x(TN/2)). NS-stage rotating
// staging LDS: [slot][A TM rows | B TN rows][4 chunks of 8 bf16], physical
// chunk = logical chunk ^ ((row>>1)&3).  K_ % BK == 0, K_/BK >= NS-1.
template <int MODE, int TM, int TN, int NS>
__global__ __launch_bounds__(256)
void gemm_bt(const __bf16* __restrict__ A, const __bf16* __restrict__ B,
             void* __restrict__ C0v, void* __restrict__ C1v, void* __restrict__ C2v,
             const float* __restrict__ b0, const float* __restrict__ b1,
             const float* __restrict__ b2, float* __restrict__ rowsum,
             int lda, int ldb, int ldc, int K_,
             long sA, long sB, long sC, int sR) {
  constexpr int BK  = 32;
  constexpr int MT  = TM / 32;          // 16-row mfma tiles per wave (M)
  constexpr int NT  = TN / 32;          // 16-col mfma tiles per wave (N)
  constexpr int CH  = 4;                // 16B chunks per row
  constexpr int SBE = (TM + TN) * BK;   // staging elems per slot
  constexpr int CP  = TN + 8;           // padded C-tile stride
  constexpr int CTE = (MODE == MODE_DIV) ? TM * CP * 2 : TM * CP;  // bf16 units
  constexpr int LDSN = (NS * SBE > CTE) ? NS * SBE : CTE;
  constexpr int LPT_A = TM * CH / 256;  // global_load_lds per thread (A)
  constexpr int LPT_B = TN * CH / 256;
  constexpr int LPT   = LPT_A + LPT_B;
  __shared__ __bf16 L[LDSN];

  const int z = blockIdx.z;
  A += (long)z * sA;
  B += (long)z * sB;

  const int tid  = threadIdx.x;
  const int lane = tid & 63;
  const int w    = tid >> 6;
  const int wm   = w >> 1, wn = w & 1;
  const int lm   = lane & 15, lq = lane >> 4;

  const int row0 = blockIdx.y * TM;
  const int col0 = blockIdx.x * TN;

  const __bf16* Ag = A + (long)row0 * lda;
  const __bf16* Bg = B + (long)col0 * ldb;

  auto issue_tile = [&](int ktv, int p) {
    __bf16* Ad = L + p * SBE;
    __bf16* Bd = Ad + TM * BK;
#pragma unroll
    for (int j = 0; j < LPT_A; ++j) {
      int s = j * 256 + tid;
      int r = s >> 2, cp = s & 3;
      int cl = cp ^ ((r >> 1) & 3);
      gload_lds16(Ag + (long)r * lda + ktv + cl * 8, Ad + j * 2048 + w * 512);
    }
#pragma unroll
    for (int j = 0; j < LPT_B; ++j) {
      int s = j * 256 + tid;
      int r = s >> 2, cp = s & 3;
      int cl = cp ^ ((r >> 1) & 3);
      gload_lds16(Bg + (long)r * ldb + ktv + cl * 8, Bd + j * 2048 + w * 512);
    }
  };

  fx4 acc[MT][NT] = {};
  const int NI = K_ / BK;

#pragma unroll
  for (int p = 0; p < NS - 1; ++p) issue_tile(p * BK, p);

  int slot = 0, nslot = NS - 1;
  for (int iter = 0; iter < NI; ++iter) {
    int nxt = iter + NS - 1;
    if (nxt < NI) {
      issue_tile(nxt * BK, nslot);
      __builtin_amdgcn_s_waitcnt(WVM((NS - 1) * LPT));  // cur tile landed
    } else {
      __builtin_amdgcn_s_waitcnt(WVM(0));
    }
    __builtin_amdgcn_s_barrier();             // all waves' cur loads landed
    __builtin_amdgcn_sched_barrier(0);        // no ds_read hoists above this
    const __bf16* Asp = L + slot * SBE;
    const __bf16* Bsp = Asp + TM * BK;
    {
      bfx8 af[MT], bfr[NT];
#pragma unroll
      for (int t = 0; t < MT; ++t) {
        int ra = wm * (TM / 2) + t * 16 + lm;
        af[t] = *(const bfx8*)(Asp + ra * BK + ((lq ^ ((ra >> 1) & 3)) << 3));
      }
#pragma unroll
      for (int t = 0; t < NT; ++t) {
        int rb = wn * (TN / 2) + t * 16 + lm;
        bfr[t] = *(const bfx8*)(Bsp + rb * BK + ((lq ^ ((rb >> 1) & 3)) << 3));
      }
#pragma unroll
      for (int mt = 0; mt < MT; ++mt)
#pragma unroll
        for (int nt = 0; nt < NT; ++nt)
          acc[mt][nt] = __builtin_amdgcn_mfma_f32_16x16x32_bf16(af[mt], bfr[nt],
                                                                acc[mt][nt], 0, 0, 0);
    }
    __builtin_amdgcn_sched_barrier(0);        // no ds_read sinks below this
    __builtin_amdgcn_s_barrier();             // readers done before overwrite
    if (++slot == NS) slot = 0;
    if (++nslot == NS) nslot = 0;
  }

  // ---- epilogue ----  C/D layout: col = lane&15, row = (lane>>4)*4 + i
  const int lr0 = wm * (TM / 2);   // + mt*16 + lq*4 + i
  const int lc0 = wn * (TN / 2);   // + nt*16 + lm

  __syncthreads();  // full fence before reusing LDS as C-tile

  if constexpr (MODE == MODE_QKV) {
    const int g   = col0 >> 9;            // 0=Q 1=K 2=V (block-uniform)
    const int gc  = col0 & 511;           // col within the g-th output
    const float* bias = (g == 0) ? b0 : ((g == 1) ? b1 : b2);
    float bvv[NT];
#pragma unroll
    for (int nt = 0; nt < NT; ++nt) bvv[nt] = bias[gc + lc0 + nt * 16 + lm];

    if (g < 2) {  // Q (pre-scaled) / K: LDS C-tile roundtrip, vectorized store
      __bf16* Ct = L;
#pragma unroll
      for (int mt = 0; mt < MT; ++mt)
#pragma unroll
        for (int nt = 0; nt < NT; ++nt)
#pragma unroll
          for (int i = 0; i < 4; ++i) {
            float v = acc[mt][nt][i] + bvv[nt];
            if (g == 0) v *= QSCALE;
            Ct[(lr0 + mt * 16 + lq * 4 + i) * CP + lc0 + nt * 16 + lm] = (__bf16)v;
          }
      __syncthreads();
      __bf16* C = (g == 0) ? (__bf16*)C0v : (__bf16*)C1v;
#pragma unroll
      for (int j = 0; j < TM * TN / 2048; ++j) {
        int s = j * 256 + tid;
        int off = s * 8;
        int r = off / TN, c = off % TN;
        *(bfx8*)(C + (long)(row0 + r) * ldc + gc + c) = *(const bfx8*)(Ct + r * CP + c);
      }
    } else {  // V, transposed: Vt[b][hid][seq], 4 consecutive seq -> 8B store
      __bf16* C = (__bf16*)C2v;
#pragma unroll
      for (int mt = 0; mt < MT; ++mt)
#pragma unroll
        for (int nt = 0; nt < NT; ++nt) {
          int c  = gc + lc0 + nt * 16 + lm;
          int rb = row0 + lr0 + mt * 16 + lq * 4;
          int b  = rb >> 12;
          int s  = rb & 4095;
          bfx4 pk;
#pragma unroll
          for (int i = 0; i < 4; ++i) pk[i] = (__bf16)(acc[mt][nt][i] + bvv[nt]);
          *(bfx4*)(C + ((long)b * HID + c) * SEQ + s) = pk;
        }
    }
  } else if constexpr (MODE == MODE_EXP) {
    __bf16* Ct = L;
    float* rsump = rowsum + (long)z * sR;
#pragma unroll
    for (int mt = 0; mt < MT; ++mt)
#pragma unroll
      for (int i = 0; i < 4; ++i) {
        int rl = lr0 + mt * 16 + lq * 4 + i;
        float rs = 0.f;
#pragma unroll
        for (int nt = 0; nt < NT; ++nt) {
          float e = EXPFN(acc[mt][nt][i]);   // Q pre-scaled: acc = score*log2e
          Ct[rl * CP + lc0 + nt * 16 + lm] = (__bf16)e;
          rs += e;
        }
        rs += __shfl_xor(rs, 1);
        rs += __shfl_xor(rs, 2);
        rs += __shfl_xor(rs, 4);
        rs += __shfl_xor(rs, 8);
        if (lm == 0) atomicAdd(&rsump[row0 + rl], rs);
      }
    __syncthreads();
    __bf16* C = ((__bf16*)C0v) + (long)z * sC;
#pragma unroll
    for (int j = 0; j < TM * TN / 2048; ++j) {
      int s = j * 256 + tid;
      int off = s * 8;
      int r = off / TN, c = off % TN;
      *(bfx8*)(C + (long)(row0 + r) * ldc + col0 + c) = *(const bfx8*)(Ct + r * CP + c);
    }
  } else {  // MODE_DIV: fp32 C-tile roundtrip, vectorized store
    float* Cf = (float*)L;
    const float* rsump = rowsum + (long)z * sR;
#pragma unroll
    for (int mt = 0; mt < MT; ++mt)
#pragma unroll
      for (int i = 0; i < 4; ++i) {
        int rl = lr0 + mt * 16 + lq * 4 + i;
        float inv = 1.f / rsump[row0 + rl];
#pragma unroll
        for (int nt = 0; nt < NT; ++nt)
          Cf[rl * CP + lc0 + nt * 16 + lm] = acc[mt][nt][i] * inv;
      }
    __syncthreads();
    float* C = ((float*)C0v) + (long)z * sC;
#pragma unroll
    for (int j = 0; j < TM * TN / 1024; ++j) {
      int s = j * 256 + tid;
      int off = s * 4;
      int r = off / TN, c = off % TN;
      *(float4*)(C + (long)(row0 + r) * ldc + col0 + c) = *(const float4*)(Cf + r * CP + c);
    }
  }
}

// ---------------------------------------------------------------------------
extern "C" void kernel_launch(void* const* d_in, const int* in_sizes, int n_in,
                              void* d_out, int out_size, void* d_ws, size_t ws_size,
                              hipStream_t stream) {
  (void)in_sizes; (void)n_in; (void)out_size; (void)ws_size;
  const float* X  = (const float*)d_in[0];
  const float* Wq = (const float*)d_in[1];
  const float* bq = (const float*)d_in[2];
  const float* Wk = (const float*)d_in[3];
  const float* bk = (const float*)d_in[4];
  const float* Wv = (const float*)d_in[5];
  const float* bv = (const float*)d_in[6];
  float* out = (float*)d_out;

  // workspace layout (bf16 elements unless noted); total ~193.6 MB
  __bf16* Xb     = (__bf16*)d_ws;                 // 16384*512
  __bf16* Wt     = Xb + (long)MROWS * HID;        // 3*512*512, [g][out][in]
  __bf16* Q      = Wt + 3 * HID * HID;            // 16384*512 (pre-scaled)
  __bf16* Kb     = Q + (long)MROWS * HID;         // 16384*512
  __bf16* Vt     = Kb + (long)MROWS * HID;        // [b][512][4096]
  float*  rowsum = (float*)(Vt + (long)MROWS * HID);  // 16384 fp32
  __bf16* E      = (__bf16*)(rowsum + MROWS);     // [b][4096][4096]

  prep_x_kernel<<<(MROWS * HID) / 1024, 256, 0, stream>>>(X, Xb);
  prep_w_kernel<<<(3 * HID * HID) / 256, 256, 0, stream>>>(Wq, Wk, Wv, Wt);

  (void)hipMemsetAsync(rowsum, 0, MROWS * sizeof(float), stream);

  // fused QKV projection: M=16384, N=1536, K=512 (NS=3, BK=32)
  gemm_bt<MODE_QKV, 128, 128, 3><<<dim3(12, 128, 1), 256, 0, stream>>>(
      Xb, Wt, Q, Kb, Vt, bq, bk, bv, nullptr,
      HID, HID, HID, HID, 0, 0, 0, 0);

  // E = exp2(Q K^T): per batch M=N=4096, K=512 (NS=3, BK=32)
  gemm_bt<MODE_EXP, 128, 128, 3><<<dim3(32, 32, NBATCH), 256, 0, stream>>>(
      Q, Kb, E, nullptr, nullptr, nullptr, nullptr, nullptr, rowsum,
      HID, HID, SEQ, HID, (long)SEQ * HID, (long)SEQ * HID, (long)SEQ * SEQ, SEQ);

  // out = (E @ Vt^T) / rowsum: per batch M=4096, N=512, K=4096 (NS=4, BK=32)
  gemm_bt<MODE_DIV, 64, 128, 4><<<dim3(4, 64, NBATCH), 256, 0, stream>>>(
      E, Vt, out, nullptr, nullptr, nullptr, nullptr, nullptr, rowsum,
      SEQ, SEQ, HID, SEQ, (long)SEQ * SEQ, (long)HID * SEQ, (long)SEQ * HID, SEQ);
}